// Round 1
// baseline (872.482 us; speedup 1.0000x reference)
//
#include <hip/hip_runtime.h>
#include <math.h>
#include <stdint.h>

// Problem constants (fixed by the reference):
#define NQ 4096    // queries
#define MP 65536   // manifold points
#define DD 64      // dims
#define QT 64      // queries per block
#define PTILE 128  // points per LDS chunk
#define PBLOCKS 16 // point stripes across grid.y
#define POINTS_PER_BLOCK (MP / PBLOCKS) // 4096
#define CHUNKS (POINTS_PER_BLOCK / PTILE) // 32

// |p|^2 per point: 16 threads/point, coalesced float4 loads, shuffle-reduce.
__global__ __launch_bounds__(256) void pnorm_k(const float* __restrict__ P,
                                               float* __restrict__ pn) {
    int g = blockIdx.x * 256 + threadIdx.x;       // MP*16 threads
    int m = g >> 4, c = g & 15;
    float4 v = reinterpret_cast<const float4*>(P)[(size_t)m * 16 + c];
    float s = v.x * v.x + v.y * v.y + v.z * v.z + v.w * v.w;
    s += __shfl_xor(s, 1);
    s += __shfl_xor(s, 2);
    s += __shfl_xor(s, 4);
    s += __shfl_xor(s, 8);
    if (c == 0) pn[m] = s;
}

// Fused dot-product + argmin. score = |p|^2 - 2 x.p (xnorm is constant per query).
// Block: 256 threads = (tq,tp) 16x16; thread tile 4 queries x 8 points.
// Query q = qBase + tq + 16*i ; point p = chunkBase + tp + 16*j (lane-interleaved
// so B LDS reads hit 16 distinct banks -> conflict-free).
__global__ __launch_bounds__(256) void argmin_k(const float* __restrict__ X,
                                                const float* __restrict__ P,
                                                const float* __restrict__ pn,
                                                unsigned long long* __restrict__ best) {
    __shared__ float Al[QT * DD];            // [q][k] stride 64 (reads are broadcast)
    __shared__ float Bl[PTILE * (DD + 1)];   // [p][k] stride 65 (bank rotation)
    const int t = threadIdx.x;
    const int qBase = blockIdx.x * QT;
    const int pStart = blockIdx.y * POINTS_PER_BLOCK;

    // Stage query tile once (perfectly coalesced; float4 LDS writes cover whole rows -> 2-way max)
    {
        const float4* X4 = reinterpret_cast<const float4*>(X + (size_t)qBase * DD);
        #pragma unroll
        for (int r = 0; r < 4; ++r) {
            int c = t + 256 * r;            // 0..1023
            float4 v = X4[c];
            int q = c >> 4, k4 = c & 15;
            *reinterpret_cast<float4*>(&Al[q * DD + k4 * 4]) = v;
        }
    }

    const int tq = t >> 4;   // 0..15
    const int tp = t & 15;   // 0..15

    float bs[4];
    int   bi[4];
    #pragma unroll
    for (int i = 0; i < 4; ++i) { bs[i] = INFINITY; bi[i] = 0; }

    for (int ch = 0; ch < CHUNKS; ++ch) {
        __syncthreads();
        // Stage 128-point chunk (coalesced global float4; scalar LDS writes, 2-way max)
        const float4* P4 = reinterpret_cast<const float4*>(P + (size_t)(pStart + ch * PTILE) * DD);
        #pragma unroll
        for (int r = 0; r < 8; ++r) {
            int c = t + 256 * r;            // 0..2047
            float4 v = P4[c];
            int m = c >> 4, k4 = c & 15;
            float* d = &Bl[m * (DD + 1) + k4 * 4];
            d[0] = v.x; d[1] = v.y; d[2] = v.z; d[3] = v.w;
        }
        __syncthreads();

        float acc[4][8];
        #pragma unroll
        for (int i = 0; i < 4; ++i)
            #pragma unroll
            for (int j = 0; j < 8; ++j) acc[i][j] = 0.f;

        #pragma unroll 4
        for (int k = 0; k < DD; ++k) {
            float a[4], b[8];
            #pragma unroll
            for (int i = 0; i < 4; ++i) a[i] = Al[(tq + 16 * i) * DD + k];      // broadcast
            #pragma unroll
            for (int j = 0; j < 8; ++j) b[j] = Bl[(tp + 16 * j) * (DD + 1) + k]; // 16 banks
            #pragma unroll
            for (int i = 0; i < 4; ++i)
                #pragma unroll
                for (int j = 0; j < 8; ++j)
                    acc[i][j] = fmaf(a[i], b[j], acc[i][j]);
        }

        // Epilogue: score and running min (strict < keeps earliest index; gp increases
        // monotonically across j and ch within a thread -> numpy first-min semantics).
        #pragma unroll
        for (int j = 0; j < 8; ++j) {
            int gp = pStart + ch * PTILE + tp + 16 * j;
            float pv = pn[gp];
            #pragma unroll
            for (int i = 0; i < 4; ++i) {
                float s = fmaf(-2.f, acc[i][j], pv);
                if (s < bs[i]) { bs[i] = s; bi[i] = gp; }
            }
        }
    }

    // Reduce across the 16 tp lanes (low 4 lane bits), tie -> lower index.
    #pragma unroll
    for (int i = 0; i < 4; ++i) {
        float s = bs[i]; int idx = bi[i];
        #pragma unroll
        for (int m = 1; m < 16; m <<= 1) {
            float so = __shfl_xor(s, m);
            int io = __shfl_xor(idx, m);
            if (so < s || (so == s && io < idx)) { s = so; idx = io; }
        }
        if (tp == 0) {
            // float -> order-preserving uint, pack with index; atomicMin merges
            // across point-stripe blocks, ties resolve to lowest index.
            unsigned u = __float_as_uint(s);
            u = (u & 0x80000000u) ? ~u : (u | 0x80000000u);
            unsigned long long key = ((unsigned long long)u << 32) | (unsigned)idx;
            atomicMin(&best[qBase + tq + 16 * i], key);
        }
    }
}

// Gather winning rows to out. 16 threads/query, coalesced float4 in/out.
__global__ __launch_bounds__(256) void gather_k(const unsigned long long* __restrict__ best,
                                                const float* __restrict__ P,
                                                float* __restrict__ out) {
    int g = blockIdx.x * 256 + threadIdx.x;  // NQ*16 threads
    int q = g >> 4, c = g & 15;
    unsigned idx = (unsigned)best[q];        // low 32 bits = index
    reinterpret_cast<float4*>(out)[g] =
        reinterpret_cast<const float4*>(P)[(size_t)idx * 16 + c];
}

extern "C" void kernel_launch(void* const* d_in, const int* in_sizes, int n_in,
                              void* d_out, int out_size, void* d_ws, size_t ws_size,
                              hipStream_t stream) {
    const float* X = (const float*)d_in[0];            // (4096, 64) f32
    const float* P = (const float*)d_in[1];            // (65536, 64) f32
    // d_in[2], d_in[3] unused by the reference output.
    float* out = (float*)d_out;                        // (4096, 64) f32

    // Workspace layout: [0, NQ*8) packed best keys; then MP floats of |p|^2.
    unsigned long long* best = (unsigned long long*)d_ws;
    float* pn = (float*)((char*)d_ws + NQ * sizeof(unsigned long long));

    // 0xFFFF... is the max sortable key -> "+inf" init. Memset is graph-capturable.
    hipMemsetAsync(d_ws, 0xFF, NQ * sizeof(unsigned long long), stream);

    pnorm_k<<<MP * 16 / 256, 256, 0, stream>>>(P, pn);

    dim3 g2(NQ / QT, PBLOCKS);                         // 64 x 16 = 1024 blocks
    argmin_k<<<g2, 256, 0, stream>>>(X, P, pn, best);

    gather_k<<<NQ * 16 / 256, 256, 0, stream>>>(best, P, out);
}

// Round 2
// 853.576 us; speedup vs baseline: 1.0221x; 1.0221x over previous
//
#include <hip/hip_runtime.h>
#include <math.h>
#include <stdint.h>

// Problem constants (fixed by the reference):
#define NQ 4096    // queries
#define MP 65536   // manifold points
#define DD 64      // dims
#define QT 64      // queries per block
#define PTILE 128  // points per LDS chunk
#define PBLOCKS 16 // point stripes across grid.y
#define POINTS_PER_BLOCK (MP / PBLOCKS) // 4096
#define CHUNKS (POINTS_PER_BLOCK / PTILE) // 32
#define STRIDE 68  // LDS row stride in floats: 68%32=4 -> bank rotation, 16B-aligned rows

// |p|^2 per point: 16 threads/point, coalesced float4 loads, shuffle-reduce.
__global__ __launch_bounds__(256) void pnorm_k(const float* __restrict__ P,
                                               float* __restrict__ pn) {
    int g = blockIdx.x * 256 + threadIdx.x;       // MP*16 threads
    int m = g >> 4, c = g & 15;
    float4 v = reinterpret_cast<const float4*>(P)[(size_t)m * 16 + c];
    float s = v.x * v.x + v.y * v.y + v.z * v.z + v.w * v.w;
    s += __shfl_xor(s, 1);
    s += __shfl_xor(s, 2);
    s += __shfl_xor(s, 4);
    s += __shfl_xor(s, 8);
    if (c == 0) pn[m] = s;
}

// Fused dot-product + argmin. score = |p|^2 - 2 x.p (|x|^2 constant per query).
// Block: 256 threads = (tq,tp) 16x16; thread tile 4 queries x 8 points.
// k-vectorized LDS reads: ds_read_b128 over 4 consecutive k, stride-68 rows.
__global__ __launch_bounds__(256) void argmin_k(const float* __restrict__ X,
                                                const float* __restrict__ P,
                                                const float* __restrict__ pn,
                                                unsigned long long* __restrict__ best) {
    __shared__ float Al[QT * STRIDE];      // [q][k] stride 68
    __shared__ float Bl[PTILE * STRIDE];   // [p][k] stride 68
    __shared__ float pns[PTILE];           // |p|^2 for the current chunk
    const int t = threadIdx.x;
    const int qBase = blockIdx.x * QT;
    const int pStart = blockIdx.y * POINTS_PER_BLOCK;

    // Stage query tile once (coalesced global float4; b128 LDS writes, <=2-way)
    {
        const float4* X4 = reinterpret_cast<const float4*>(X + (size_t)qBase * DD);
        #pragma unroll
        for (int r = 0; r < 4; ++r) {
            int c = t + 256 * r;            // 0..1023
            float4 v = X4[c];
            int q = c >> 4, k4 = c & 15;
            *reinterpret_cast<float4*>(&Al[q * STRIDE + k4 * 4]) = v;
        }
    }

    const int tq = t >> 4;   // 0..15
    const int tp = t & 15;   // 0..15

    float bs[4];
    int   bi[4];
    #pragma unroll
    for (int i = 0; i < 4; ++i) { bs[i] = INFINITY; bi[i] = 0; }

    for (int ch = 0; ch < CHUNKS; ++ch) {
        __syncthreads();
        // Stage 128-point chunk + its |p|^2 (coalesced global float4)
        const int pChunk = pStart + ch * PTILE;
        const float4* P4 = reinterpret_cast<const float4*>(P + (size_t)pChunk * DD);
        #pragma unroll
        for (int r = 0; r < 8; ++r) {
            int c = t + 256 * r;            // 0..2047
            float4 v = P4[c];
            int m = c >> 4, k4 = c & 15;
            *reinterpret_cast<float4*>(&Bl[m * STRIDE + k4 * 4]) = v;
        }
        if (t < PTILE) pns[t] = pn[pChunk + t];
        __syncthreads();

        float acc[4][8];
        #pragma unroll
        for (int i = 0; i < 4; ++i)
            #pragma unroll
            for (int j = 0; j < 8; ++j) acc[i][j] = 0.f;

        #pragma unroll 4
        for (int kg = 0; kg < DD / 4; ++kg) {   // 16 k-groups of 4
            float4 a4[4], b4[8];
            #pragma unroll
            for (int i = 0; i < 4; ++i)
                a4[i] = *reinterpret_cast<const float4*>(&Al[(tq + 16 * i) * STRIDE + kg * 4]);
            #pragma unroll
            for (int j = 0; j < 8; ++j)
                b4[j] = *reinterpret_cast<const float4*>(&Bl[(tp + 16 * j) * STRIDE + kg * 4]);
            #pragma unroll
            for (int i = 0; i < 4; ++i)
                #pragma unroll
                for (int j = 0; j < 8; ++j) {
                    acc[i][j] = fmaf(a4[i].x, b4[j].x, acc[i][j]);
                    acc[i][j] = fmaf(a4[i].y, b4[j].y, acc[i][j]);
                    acc[i][j] = fmaf(a4[i].z, b4[j].z, acc[i][j]);
                    acc[i][j] = fmaf(a4[i].w, b4[j].w, acc[i][j]);
                }
        }

        // Epilogue: score and running min (strict < keeps earliest index; gp increases
        // monotonically across j and ch within a thread -> numpy first-min semantics).
        #pragma unroll
        for (int j = 0; j < 8; ++j) {
            int gp = pChunk + tp + 16 * j;
            float pv = pns[tp + 16 * j];
            #pragma unroll
            for (int i = 0; i < 4; ++i) {
                float s = fmaf(-2.f, acc[i][j], pv);
                if (s < bs[i]) { bs[i] = s; bi[i] = gp; }
            }
        }
    }

    // Reduce across the 16 tp lanes (low 4 lane bits), tie -> lower index.
    #pragma unroll
    for (int i = 0; i < 4; ++i) {
        float s = bs[i]; int idx = bi[i];
        #pragma unroll
        for (int m = 1; m < 16; m <<= 1) {
            float so = __shfl_xor(s, m);
            int io = __shfl_xor(idx, m);
            if (so < s || (so == s && io < idx)) { s = so; idx = io; }
        }
        if (tp == 0) {
            // float -> order-preserving uint, pack with index; atomicMin merges
            // across point-stripe blocks, ties resolve to lowest index.
            unsigned u = __float_as_uint(s);
            u = (u & 0x80000000u) ? ~u : (u | 0x80000000u);
            unsigned long long key = ((unsigned long long)u << 32) | (unsigned)idx;
            atomicMin(&best[qBase + tq + 16 * i], key);
        }
    }
}

// Gather winning rows to out. 16 threads/query, coalesced float4 in/out.
__global__ __launch_bounds__(256) void gather_k(const unsigned long long* __restrict__ best,
                                                const float* __restrict__ P,
                                                float* __restrict__ out) {
    int g = blockIdx.x * 256 + threadIdx.x;  // NQ*16 threads
    int q = g >> 4, c = g & 15;
    unsigned idx = (unsigned)best[q];        // low 32 bits = index
    reinterpret_cast<float4*>(out)[g] =
        reinterpret_cast<const float4*>(P)[(size_t)idx * 16 + c];
}

extern "C" void kernel_launch(void* const* d_in, const int* in_sizes, int n_in,
                              void* d_out, int out_size, void* d_ws, size_t ws_size,
                              hipStream_t stream) {
    const float* X = (const float*)d_in[0];            // (4096, 64) f32
    const float* P = (const float*)d_in[1];            // (65536, 64) f32
    // d_in[2], d_in[3] unused by the reference output.
    float* out = (float*)d_out;                        // (4096, 64) f32

    // Workspace layout: [0, NQ*8) packed best keys; then MP floats of |p|^2.
    unsigned long long* best = (unsigned long long*)d_ws;
    float* pn = (float*)((char*)d_ws + NQ * sizeof(unsigned long long));

    // 0xFFFF... is the max sortable key -> "+inf" init. Memset is graph-capturable.
    hipMemsetAsync(d_ws, 0xFF, NQ * sizeof(unsigned long long), stream);

    pnorm_k<<<MP * 16 / 256, 256, 0, stream>>>(P, pn);

    dim3 g2(NQ / QT, PBLOCKS);                         // 64 x 16 = 1024 blocks
    argmin_k<<<g2, 256, 0, stream>>>(X, P, pn, best);

    gather_k<<<NQ * 16 / 256, 256, 0, stream>>>(best, P, out);
}

// Round 3
// 548.247 us; speedup vs baseline: 1.5914x; 1.5569x over previous
//
#include <hip/hip_runtime.h>
#include <math.h>
#include <stdint.h>

// Problem constants (fixed by the reference):
#define NQ 4096    // queries
#define MP 65536   // manifold points
#define DD 64      // dims
#define QT 64      // queries per block
#define PCHUNK 128 // points staged per chunk
#define PBLOCKS 16 // point stripes
#define PPB (MP / PBLOCKS)    // 4096 points per block
#define CHUNKS (PPB / PCHUNK) // 32
#define LSTR 72    // LDS row stride in fp16 (36 dwords -> uniform bank stacking)

typedef _Float16 f16;
typedef _Float16 f16x4 __attribute__((ext_vector_type(4)));
typedef _Float16 f16x8 __attribute__((ext_vector_type(8)));
typedef float f32x4 __attribute__((ext_vector_type(4)));

// |p|^2 per point, exact fp32: 16 threads/point, float4 loads, shuffle-reduce.
__global__ __launch_bounds__(256) void pnorm_k(const float* __restrict__ P,
                                               float* __restrict__ pn) {
    int g = blockIdx.x * 256 + threadIdx.x;       // MP*16 threads
    int m = g >> 4, c = g & 15;
    float4 v = reinterpret_cast<const float4*>(P)[(size_t)m * 16 + c];
    float s = v.x * v.x + v.y * v.y + v.z * v.z + v.w * v.w;
    s += __shfl_xor(s, 1);
    s += __shfl_xor(s, 2);
    s += __shfl_xor(s, 4);
    s += __shfl_xor(s, 8);
    if (c == 0) pn[m] = s;
}

// Fused split-fp16 MFMA dot + argmin. score = |p|^2 - 2 x.p ; x.p via
// ah*bh + ah*bl + al*bh (error ~2^-22 rel; |p|^2 exact fp32).
// A-operand = points (row=point), B-operand = queries (col=query).
// Block: 256 thr = 4 waves; block tile 64q x 128p/chunk; wave = 32p x 64q.
__global__ __launch_bounds__(256) void argmin_k(const float* __restrict__ X,
                                                const float* __restrict__ P,
                                                const float* __restrict__ pn,
                                                unsigned long long* __restrict__ best) {
    __shared__ f16 AH[PCHUNK * LSTR];   // hi fp16 (Q tile staged here first)
    __shared__ f16 AL[PCHUNK * LSTR];   // lo fp16
    __shared__ float pns[PCHUNK];

    const int t = threadIdx.x;
    // XCD swizzle (dispatch round-robin heuristic): consecutive blocks on one
    // XCD share a point stripe -> stripe (1 MB fp32) stays L2-resident.
    const int b = blockIdx.x;               // 0..1023
    const int xcd = b & 7;
    const int seq = b >> 3;                 // per-XCD dispatch order
    const int yStripe = seq >> 3;           // 0..15
    const int xq = ((seq & 7) << 3) | xcd;  // 0..63, bijective with (b)
    const int qBase = xq * QT;
    const int pStart = yStripe * PPB;

    const int lane = t & 63;
    const int w = t >> 6;        // wave 0..3 -> points w*32..w*32+31 of chunk
    const int n16 = lane & 15;
    const int quad = lane >> 4;

    // ---- Stage query tile (64x64 fp32 -> hi/lo fp16 in AH/AL), coalesced.
    {
        const float4* X4 = reinterpret_cast<const float4*>(X + (size_t)qBase * DD);
        #pragma unroll
        for (int r = 0; r < 4; ++r) {
            int c = t + 256 * r;            // 0..1023
            float4 v = X4[c];
            int q = c >> 4, k4 = c & 15;
            f16x4 h, l;
            h.x = (f16)v.x; l.x = (f16)(v.x - (float)h.x);
            h.y = (f16)v.y; l.y = (f16)(v.y - (float)h.y);
            h.z = (f16)v.z; l.z = (f16)(v.z - (float)h.z);
            h.w = (f16)v.w; l.w = (f16)(v.w - (float)h.w);
            *reinterpret_cast<f16x4*>(&AH[q * LSTR + k4 * 4]) = h;
            *reinterpret_cast<f16x4*>(&AL[q * LSTR + k4 * 4]) = l;
        }
    }
    __syncthreads();

    // B-operand (query) fragments, held in registers for the whole kernel:
    // lane holds Q[n = nt*16 + n16][k = kh*32 + quad*8 + j], j=0..7.
    f16x8 QH[4][2], QL[4][2];
    #pragma unroll
    for (int nt = 0; nt < 4; ++nt)
        #pragma unroll
        for (int kh = 0; kh < 2; ++kh) {
            int row = nt * 16 + n16, ko = kh * 32 + quad * 8;
            QH[nt][kh] = *reinterpret_cast<const f16x8*>(&AH[row * LSTR + ko]);
            QL[nt][kh] = *reinterpret_cast<const f16x8*>(&AL[row * LSTR + ko]);
        }

    float bs[4];
    int   bi[4];
    #pragma unroll
    for (int nt = 0; nt < 4; ++nt) { bs[nt] = INFINITY; bi[nt] = 0; }

    for (int ch = 0; ch < CHUNKS; ++ch) {
        __syncthreads();  // protect AH/AL vs Q-frag loads / previous compute
        const int pChunk = pStart + ch * PCHUNK;
        const float4* P4 = reinterpret_cast<const float4*>(P + (size_t)pChunk * DD);
        #pragma unroll
        for (int r = 0; r < 8; ++r) {
            int c = t + 256 * r;            // 0..2047
            float4 v = P4[c];
            int pt = c >> 4, k4 = c & 15;
            f16x4 h, l;
            h.x = (f16)v.x; l.x = (f16)(v.x - (float)h.x);
            h.y = (f16)v.y; l.y = (f16)(v.y - (float)h.y);
            h.z = (f16)v.z; l.z = (f16)(v.z - (float)h.z);
            h.w = (f16)v.w; l.w = (f16)(v.w - (float)h.w);
            *reinterpret_cast<f16x4*>(&AH[pt * LSTR + k4 * 4]) = h;
            *reinterpret_cast<f16x4*>(&AL[pt * LSTR + k4 * 4]) = l;
        }
        if (t < PCHUNK) pns[t] = pn[pChunk + t];
        __syncthreads();

        f32x4 acc[2][4];
        #pragma unroll
        for (int mt = 0; mt < 2; ++mt)
            #pragma unroll
            for (int nt = 0; nt < 4; ++nt)
                acc[mt][nt] = (f32x4){0.f, 0.f, 0.f, 0.f};

        #pragma unroll
        for (int mt = 0; mt < 2; ++mt) {
            // A-operand (point) fragments: row = w*32 + mt*16 + n16.
            f16x8 PH[2], PL[2];
            #pragma unroll
            for (int kh = 0; kh < 2; ++kh) {
                int row = w * 32 + mt * 16 + n16, ko = kh * 32 + quad * 8;
                PH[kh] = *reinterpret_cast<const f16x8*>(&AH[row * LSTR + ko]);
                PL[kh] = *reinterpret_cast<const f16x8*>(&AL[row * LSTR + ko]);
            }
            #pragma unroll
            for (int nt = 0; nt < 4; ++nt)
                #pragma unroll
                for (int kh = 0; kh < 2; ++kh) {
                    acc[mt][nt] = __builtin_amdgcn_mfma_f32_16x16x32_f16(PH[kh], QH[nt][kh], acc[mt][nt], 0, 0, 0);
                    acc[mt][nt] = __builtin_amdgcn_mfma_f32_16x16x32_f16(PH[kh], QL[nt][kh], acc[mt][nt], 0, 0, 0);
                    acc[mt][nt] = __builtin_amdgcn_mfma_f32_16x16x32_f16(PL[kh], QH[nt][kh], acc[mt][nt], 0, 0, 0);
                }
        }

        // Epilogue: C/D layout col=lane&15 (query), row=quad*4+r (point).
        // Point idx ascends over (mt, r) per lane -> strict < keeps lowest idx.
        #pragma unroll
        for (int mt = 0; mt < 2; ++mt)
            #pragma unroll
            for (int r = 0; r < 4; ++r) {
                int lrow = w * 32 + mt * 16 + quad * 4 + r;
                float pv = pns[lrow];
                int gp = pChunk + lrow;
                #pragma unroll
                for (int nt = 0; nt < 4; ++nt) {
                    float sc = fmaf(-2.f, acc[mt][nt][r], pv);
                    if (sc < bs[nt]) { bs[nt] = sc; bi[nt] = gp; }
                }
            }
    }

    // Reduce over quads (lane bits 4,5), tie -> lower point index.
    #pragma unroll
    for (int nt = 0; nt < 4; ++nt) {
        float sv = bs[nt]; int iv = bi[nt];
        #pragma unroll
        for (int m = 16; m < 64; m <<= 1) {
            float so = __shfl_xor(sv, m);
            int   io = __shfl_xor(iv, m);
            if (so < sv || (so == sv && io < iv)) { sv = so; iv = io; }
        }
        if (quad == 0) {
            unsigned u = __float_as_uint(sv);
            u = (u & 0x80000000u) ? ~u : (u | 0x80000000u);
            unsigned long long key = ((unsigned long long)u << 32) | (unsigned)iv;
            atomicMin(&best[qBase + nt * 16 + n16], key);
        }
    }
}

// Gather winning rows to out. 16 threads/query, coalesced float4 in/out.
__global__ __launch_bounds__(256) void gather_k(const unsigned long long* __restrict__ best,
                                                const float* __restrict__ P,
                                                float* __restrict__ out) {
    int g = blockIdx.x * 256 + threadIdx.x;  // NQ*16 threads
    int q = g >> 4, c = g & 15;
    unsigned idx = (unsigned)best[q];        // low 32 bits = index
    reinterpret_cast<float4*>(out)[g] =
        reinterpret_cast<const float4*>(P)[(size_t)idx * 16 + c];
}

extern "C" void kernel_launch(void* const* d_in, const int* in_sizes, int n_in,
                              void* d_out, int out_size, void* d_ws, size_t ws_size,
                              hipStream_t stream) {
    const float* X = (const float*)d_in[0];            // (4096, 64) f32
    const float* P = (const float*)d_in[1];            // (65536, 64) f32
    // d_in[2], d_in[3] unused by the reference output.
    float* out = (float*)d_out;                        // (4096, 64) f32

    // Workspace: [0, NQ*8) packed best keys; then MP floats of |p|^2.
    unsigned long long* best = (unsigned long long*)d_ws;
    float* pn = (float*)((char*)d_ws + NQ * sizeof(unsigned long long));

    hipMemsetAsync(d_ws, 0xFF, NQ * sizeof(unsigned long long), stream);

    pnorm_k<<<MP * 16 / 256, 256, 0, stream>>>(P, pn);

    argmin_k<<<(NQ / QT) * PBLOCKS, 256, 0, stream>>>(X, P, pn, best);

    gather_k<<<NQ * 16 / 256, 256, 0, stream>>>(best, P, out);
}

// Round 4
// 419.606 us; speedup vs baseline: 2.0793x; 1.3066x over previous
//
#include <hip/hip_runtime.h>
#include <math.h>
#include <stdint.h>

// Problem constants (fixed by the reference):
#define NQ 4096    // queries
#define MP 65536   // manifold points
#define DD 64      // dims
#define QT 64      // queries per block (4 nt tiles of 16)
#define STRIPES 8  // point stripes == XCDs; stripe s runs on XCD s (b&7 heuristic)
#define PPB (MP / STRIPES)      // 8192 points per stripe
#define GPS (PPB / 16)          // 512 groups (of 16 points) per stripe
#define PGROUPS (MP / 16)       // 4096 point groups
#define XGROUPS (NQ / 16)       // 256 query groups

typedef _Float16 f16;
typedef _Float16 f16x8 __attribute__((ext_vector_type(8)));
typedef float f32x4 __attribute__((ext_vector_type(4)));

// Fragment-swizzled layout (per 16-row group g):
//   FR[((g*2 + sel)*2 + kh)*512 + lane*8]  : 8 f16 = 16 B per lane
//   sel: 0=hi, 1=lo ; kh: K-half (k = kh*32 + quad*8 + j) ; lane: n16=lane&15 is
//   the row, quad=lane>>4 picks the k-octet — exactly the gfx950 16x16x32 A/B
//   per-lane operand layout (validated end-to-end in R3, absmax 0).

// One-shot pre-swizzle: fp32 rows -> hi/lo fp16 fragment order; also 0.5*|p|^2.
// Tasks 0..4095 = P groups, 4096..4351 = X groups. 4 groups per block (1/wave).
__global__ __launch_bounds__(256) void prep_k(const float* __restrict__ P,
                                              const float* __restrict__ X,
                                              f16* __restrict__ PF,
                                              f16* __restrict__ XF,
                                              float* __restrict__ pnh) {
    const int w = threadIdx.x >> 6, lane = threadIdx.x & 63;
    const int n16 = lane & 15, quad = lane >> 4;
    const int task = blockIdx.x * 4 + w;
    const float* src; f16* dst; int g; bool dopn;
    if (task < PGROUPS) { src = P; dst = PF; g = task; dopn = true; }
    else                { src = X; dst = XF; g = task - PGROUPS; dopn = false; }

    const float* row = src + ((size_t)g * 16 + n16) * DD;
    float ss = 0.f;
    #pragma unroll
    for (int kh = 0; kh < 2; ++kh) {
        float4 v0 = *reinterpret_cast<const float4*>(row + kh * 32 + quad * 8);
        float4 v1 = *reinterpret_cast<const float4*>(row + kh * 32 + quad * 8 + 4);
        float vv[8] = {v0.x, v0.y, v0.z, v0.w, v1.x, v1.y, v1.z, v1.w};
        f16x8 h, l;
        #pragma unroll
        for (int j = 0; j < 8; ++j) {
            f16 hh = (f16)vv[j];
            h[j] = hh;
            l[j] = (f16)(vv[j] - (float)hh);
            ss = fmaf(vv[j], vv[j], ss);
        }
        *reinterpret_cast<f16x8*>(dst + ((size_t)(g * 2 + 0) * 2 + kh) * 512 + lane * 8) = h;
        *reinterpret_cast<f16x8*>(dst + ((size_t)(g * 2 + 1) * 2 + kh) * 512 + lane * 8) = l;
    }
    if (dopn) {
        ss += __shfl_xor(ss, 16);   // reduce across quads (k-octets)
        ss += __shfl_xor(ss, 32);
        if (quad == 0) pnh[g * 16 + n16] = 0.5f * ss;
    }
}

// Fused split-fp16 MFMA dot + argmin, zero LDS / zero barriers.
// score' = x.p - 0.5|p|^2 (maximize) ; x.p via ah*bh + ah*bl + al*bh.
// Block 256 = 4 waves; each wave: 64 queries x (its quarter of the stripe).
// Grid 512 = 64 qtiles x 8 stripes; stripe = b&7 -> one stripe per XCD,
// PF stripe (2 MB) stays L2-resident for the whole kernel.
__global__ __launch_bounds__(256, 2) void argmin_k(const f16* __restrict__ PF,
                                                   const f16* __restrict__ XF,
                                                   const float* __restrict__ pnh,
                                                   unsigned long long* __restrict__ best) {
    const int t = threadIdx.x;
    const int lane = t & 63, w = t >> 6;
    const int n16 = lane & 15, quad = lane >> 4;
    const int b = blockIdx.x;
    const int stripe = b & 7;
    const int qBase = (b >> 3) * QT;

    // Query fragments, held in registers for the whole kernel.
    f16x8 QH[4][2], QL[4][2];
    {
        const int qg0 = qBase >> 4;
        #pragma unroll
        for (int nt = 0; nt < 4; ++nt)
            #pragma unroll
            for (int kh = 0; kh < 2; ++kh) {
                const f16* o = XF + ((size_t)(qg0 + nt) * 4 + kh) * 512 + lane * 8;
                QH[nt][kh] = *reinterpret_cast<const f16x8*>(o);
                QL[nt][kh] = *reinterpret_cast<const f16x8*>(o + 1024);
            }
    }

    float rmax[4];
    int   ridx[4];
    #pragma unroll
    for (int nt = 0; nt < 4; ++nt) { rmax[nt] = -INFINITY; ridx[nt] = 0; }

    auto PROC = [&](int gg, f16x8* PH, f16x8* PL) {
        f32x4 pq = *reinterpret_cast<const f32x4*>(pnh + gg * 16 + quad * 4);
        #pragma unroll
        for (int nt = 0; nt < 4; ++nt) {
            f32x4 a = {0.f, 0.f, 0.f, 0.f};
            #pragma unroll
            for (int kh = 0; kh < 2; ++kh) {
                a = __builtin_amdgcn_mfma_f32_16x16x32_f16(PH[kh], QH[nt][kh], a, 0, 0, 0);
                a = __builtin_amdgcn_mfma_f32_16x16x32_f16(PH[kh], QL[nt][kh], a, 0, 0, 0);
                a = __builtin_amdgcn_mfma_f32_16x16x32_f16(PL[kh], QH[nt][kh], a, 0, 0, 0);
            }
            // C/D: col=lane&15 (query), row=quad*4+r (point) — R3-validated.
            float s0 = a[0] - pq[0], s1 = a[1] - pq[1];
            float s2 = a[2] - pq[2], s3 = a[3] - pq[3];
            float smax = fmaxf(fmaxf(s0, s1), fmaxf(s2, s3));
            if (smax > rmax[nt]) {      // strict > keeps earliest (lowest) group
                rmax[nt] = smax;
                int r = 3;              // descending chain -> lowest matching r
                r = (s2 == smax) ? 2 : r;
                r = (s1 == smax) ? 1 : r;
                r = (s0 == smax) ? 0 : r;
                ridx[nt] = gg * 16 + quad * 4 + r;
            }
        }
    };

    // Double-buffered group loop: wave w covers groups stripe*GPS + w + 4*j.
    int g = stripe * GPS + w;
    f16x8 PHa[2], PLa[2], PHb[2], PLb[2];
    {
        const f16* f0 = PF + (size_t)g * 2048 + lane * 8;
        PHa[0] = *reinterpret_cast<const f16x8*>(f0);
        PHa[1] = *reinterpret_cast<const f16x8*>(f0 + 512);
        PLa[0] = *reinterpret_cast<const f16x8*>(f0 + 1024);
        PLa[1] = *reinterpret_cast<const f16x8*>(f0 + 1536);
    }
    for (int i = 0; i < GPS / 4; i += 2) {
        {   // prefetch group g+4 into buffer b
            const f16* fn = PF + (size_t)(g + 4) * 2048 + lane * 8;
            PHb[0] = *reinterpret_cast<const f16x8*>(fn);
            PHb[1] = *reinterpret_cast<const f16x8*>(fn + 512);
            PLb[0] = *reinterpret_cast<const f16x8*>(fn + 1024);
            PLb[1] = *reinterpret_cast<const f16x8*>(fn + 1536);
        }
        PROC(g, PHa, PLa);
        {   // prefetch group g+8 into buffer a (tail-guarded, re-reads g)
            int gp = (i + 2 < GPS / 4) ? g + 8 : g;
            const f16* fn = PF + (size_t)gp * 2048 + lane * 8;
            PHa[0] = *reinterpret_cast<const f16x8*>(fn);
            PHa[1] = *reinterpret_cast<const f16x8*>(fn + 512);
            PLa[0] = *reinterpret_cast<const f16x8*>(fn + 1024);
            PLa[1] = *reinterpret_cast<const f16x8*>(fn + 1536);
        }
        PROC(g + 4, PHb, PLb);
        g += 8;
    }

    // Reduce across quads (lane bits 4,5): larger score', tie -> lower index.
    #pragma unroll
    for (int nt = 0; nt < 4; ++nt) {
        float sv = rmax[nt]; int iv = ridx[nt];
        #pragma unroll
        for (int m = 16; m < 64; m <<= 1) {
            float so = __shfl_xor(sv, m);
            int   io = __shfl_xor(iv, m);
            if (so > sv || (so == sv && io < iv)) { sv = so; iv = io; }
        }
        if (quad == 0) {
            float s = -2.f * sv;                       // back to d^2-|x|^2 scale
            unsigned u = __float_as_uint(s);
            u = (u & 0x80000000u) ? ~u : (u | 0x80000000u);
            unsigned long long key = ((unsigned long long)u << 32) | (unsigned)iv;
            atomicMin(&best[qBase + nt * 16 + n16], key);
        }
    }
}

// Gather winning rows to out. 16 threads/query, coalesced float4 in/out.
__global__ __launch_bounds__(256) void gather_k(const unsigned long long* __restrict__ best,
                                                const float* __restrict__ P,
                                                float* __restrict__ out) {
    int g = blockIdx.x * 256 + threadIdx.x;  // NQ*16 threads
    int q = g >> 4, c = g & 15;
    unsigned idx = (unsigned)best[q];        // low 32 bits = index
    reinterpret_cast<float4*>(out)[g] =
        reinterpret_cast<const float4*>(P)[(size_t)idx * 16 + c];
}

extern "C" void kernel_launch(void* const* d_in, const int* in_sizes, int n_in,
                              void* d_out, int out_size, void* d_ws, size_t ws_size,
                              hipStream_t stream) {
    const float* X = (const float*)d_in[0];            // (4096, 64) f32
    const float* P = (const float*)d_in[1];            // (65536, 64) f32
    // d_in[2], d_in[3] unused by the reference output.
    float* out = (float*)d_out;                        // (4096, 64) f32

    // Workspace layout (all 16B-aligned):
    //   best @ 0           : NQ * 8 B        = 32 KB
    //   pnh  @ 32768       : MP * 4 B        = 256 KB   (0.5*|p|^2)
    //   XF   @ 294912      : NQ*DD*2*2 B     = 1 MB     (query frags hi/lo)
    //   PF   @ 1343488     : MP*DD*2*2 B     = 16 MB    (point frags hi/lo)
    unsigned long long* best = (unsigned long long*)d_ws;
    float* pnh = (float*)((char*)d_ws + 32768);
    f16*   XF  = (f16*)((char*)d_ws + 294912);
    f16*   PF  = (f16*)((char*)d_ws + 1343488);

    hipMemsetAsync(d_ws, 0xFF, NQ * sizeof(unsigned long long), stream);

    prep_k<<<(PGROUPS + XGROUPS) / 4, 256, 0, stream>>>(P, X, PF, XF, pnh);

    argmin_k<<<(NQ / QT) * STRIPES, 256, 0, stream>>>(PF, XF, pnh, best);

    gather_k<<<NQ * 16 / 256, 256, 0, stream>>>(best, P, out);
}